// Round 4
// baseline (234.118 us; speedup 1.0000x reference)
//
#include <hip/hip_runtime.h>

typedef __attribute__((ext_vector_type(8))) short short8;
typedef __attribute__((ext_vector_type(4))) float f32x4;
typedef __attribute__((ext_vector_type(2))) float f32x2;
typedef __attribute__((ext_vector_type(4))) unsigned int uint4v;
typedef unsigned short u16;

#define NI 2048   // input capsules
// B=64, J=32, D=16, E=16, JD=512. Inputs fp32; compute bf16 MFMA.

// bf16 RNE pack of two floats -> dword (lo=a, hi=b)
__device__ __forceinline__ unsigned int packbf2(float a, float b){
  unsigned int ua = __float_as_uint(a), ub = __float_as_uint(b);
  unsigned int ra = (ua + 0x7FFFu + ((ua >> 16) & 1u)) >> 16;
  unsigned int rb = (ub + 0x7FFFu + ((ub >> 16) & 1u)) & 0xFFFF0000u;
  return ra | rb;
}
__device__ __forceinline__ float bflo(unsigned int p){ return __uint_as_float(p << 16); }
__device__ __forceinline__ float bfhi(unsigned int p){ return __uint_as_float(p & 0xFFFF0000u); }

__device__ __forceinline__ uint4v cvt8(const f32x4& a, const f32x4& b){
  uint4v p = { packbf2(a.x, a.y), packbf2(a.z, a.w),
               packbf2(b.x, b.y), packbf2(b.z, b.w) };
  return p;
}

// async global->LDS, 16 B per lane; lds dest = wave-uniform base + lane*16
__device__ __forceinline__ void gl_lds16(const void* g, void* l){
  __builtin_amdgcn_global_load_lds(
      (const __attribute__((address_space(1))) unsigned int*)g,
      (__attribute__((address_space(3))) unsigned int*)l, 16, 0, 0);
}

__device__ __forceinline__ f32x4 squash4(const f32x4& q){
  f32x4 f;
  f.x = q.x / ((1.f + q.x) * sqrtf(q.x + 1e-8f));
  f.y = q.y / ((1.f + q.y) * sqrtf(q.y + 1e-8f));
  f.z = q.z / ((1.f + q.z) * sqrtf(q.z + 1e-8f));
  f.w = q.w / ((1.f + q.w) * sqrtf(q.w + 1e-8f));
  return f;
}

// ============================================================================
// FUSED persistent kernel: 256 blocks x 512 threads, 1 block/CU (156672 B LDS).
// Each block owns 8 W rows, bf16-resident in LDS across all 3 routing passes.
// Exchange uses NORMAL cached loads/stores (L2 write-back; bulk full-line
// writebacks at barriers) + single-sided agent fences in a tree grid barrier:
// release = fence(RELEASE) [L2 wb] by t0 before arrival; acquire =
// fence(ACQUIRE) [L1/L2 inv] by t0 after release observed.
// ============================================================================

#define FUSED_SMEM 156672

// pass body. MODE 0: uniform c (2 i's packed into K=32).
// MODE 1: c = softmax_j(u . v1), v1 = S1*f(q1) computed inline.
// MODE 2: same with v12 = S1*f(q1) + S2*f(q2).
template<int MODE>
__device__ __forceinline__ void pass_phase(
    const u16* __restrict__ sW, const u16* __restrict__ sX,
    float* __restrict__ sSumA, float* __restrict__ sSumB,
    const float* __restrict__ Sv1, const float* __restrict__ qv1,
    const float* __restrict__ Sv2, const float* __restrict__ qv2,
    float* __restrict__ partials, int blk, int t)
{
  const int w = t >> 6, lane = t & 63;
  const int wtile = w & 1, jhalf = (w >> 1) & 1, bh = w >> 2;
  const int lq = lane >> 4, lb = lane & 15, qs = lq & 1;
  const int bg = bh * 32 + wtile * 16 + lb;   // this lane's output column b
  const short8 zero8 = {0,0,0,0,0,0,0,0};
  const f32x4 zf4 = {0.f,0.f,0.f,0.f};

  f32x4 acc[16];
  #pragma unroll
  for (int tj = 0; tj < 16; ++tj) acc[tj] = zf4;

  unsigned int vpl[16], vph[16];
  if constexpr (MODE >= 1){
    // reconstruct v inline: v = S1*f(q1) (+ S2*f(q2) for MODE 2)
    f32x4 qa = *(const f32x4*)(qv1 + bg * 16 + lq * 4);
    f32x4 fa = squash4(qa);
    f32x4 fb = zf4;
    if constexpr (MODE == 2){
      f32x4 qb = *(const f32x4*)(qv2 + bg * 16 + lq * 4);
      fb = squash4(qb);
    }
    #pragma unroll
    for (int tj = 0; tj < 16; ++tj){
      int jd = (jhalf * 16 + tj) * 16 + lq * 4;
      f32x4 sv = *(const f32x4*)(Sv1 + bg * 512 + jd);
      f32x4 v;
      v.x = sv.x * fa.x; v.y = sv.y * fa.y; v.z = sv.z * fa.z; v.w = sv.w * fa.w;
      if constexpr (MODE == 2){
        f32x4 s2 = *(const f32x4*)(Sv2 + bg * 512 + jd);
        v.x += s2.x * fb.x; v.y += s2.y * fb.y; v.z += s2.z * fb.z; v.w += s2.w * fb.w;
      }
      vpl[tj] = packbf2(v.x, v.y);
      vph[tj] = packbf2(v.z, v.w);
    }
  }

  if constexpr (MODE == 0){
    // K=32 packs 2 i-rows: quads 0,1 -> row 2s, quads 2,3 -> row 2s+1
    const int rsel = lq >> 1;
    #pragma unroll
    for (int s = 0; s < 4; ++s){
      const u16* wrow = sW + (size_t)(2 * s + rsel) * 8192;
      const u16* xrow = sX + (size_t)(2 * s + rsel) * 1024;
      short8 bfrag = *(const short8*)(xrow + bg * 16 + qs * 8);
      #pragma unroll
      for (int tj = 0; tj < 16; ++tj){
        int j = jhalf * 16 + tj;
        short8 afrag = *(const short8*)(wrow + j * 256 + lb * 16 + qs * 8);
        acc[tj] = __builtin_amdgcn_mfma_f32_16x16x32_bf16(afrag, bfrag, acc[tj], 0, 0, 0);
      }
    }
  } else {
    for (int s = 0; s < 8; ++s){
      const u16* wrow = sW + (size_t)s * 8192;
      const u16* xrow = sX + (size_t)s * 1024;
      short8 bl8 = *(const short8*)(xrow + bg * 16 + qs * 8);
      short8 bfrag = (lq < 2) ? bl8 : zero8;   // K upper half zero (B-side mask suffices)
      f32x4 ut[16];
      float e[16];
      float ps = 0.f;
      #pragma unroll
      for (int tj = 0; tj < 16; ++tj){
        int j = jhalf * 16 + tj;
        short8 afrag = *(const short8*)(wrow + j * 256 + lb * 16 + qs * 8);
        ut[tj] = __builtin_amdgcn_mfma_f32_16x16x32_bf16(afrag, bfrag, zf4, 0, 0, 0);
        float p = ut[tj].x * bflo(vpl[tj]) + ut[tj].y * bfhi(vpl[tj])
                + ut[tj].z * bflo(vph[tj]) + ut[tj].w * bfhi(vph[tj]);
        p += __shfl_xor(p, 16, 64);
        p += __shfl_xor(p, 32, 64);   // full logit[j] on every lane
        e[tj] = __expf(p);            // |logit| small: fp32-safe without max-sub
        ps += e[tj];
      }
      // exchange partial denominator with j-half partner wave (w^2), A/B buffers
      float* sS = (s & 1) ? sSumB : sSumA;
      if (lane < 16) sS[w * 16 + lane] = ps;
      __syncthreads();
      float inv = 1.0f / (ps + sS[(w ^ 2) * 16 + lb]);
      #pragma unroll
      for (int tj = 0; tj < 16; ++tj){
        float c = e[tj] * inv;
        acc[tj].x += c * ut[tj].x;
        acc[tj].y += c * ut[tj].y;
        acc[tj].z += c * ut[tj].z;
        acc[tj].w += c * ut[tj].w;
      }
    }
  }

  // partial-sum write: normal cached stores (bulk L2 writeback at the barrier)
  float* dst = partials + ((size_t)blk * 8 + (size_t)w) * 4096 + (size_t)lane * 64;
  #pragma unroll
  for (int tj = 0; tj < 16; ++tj) *(f32x4*)(dst + tj * 4) = acc[tj];
}

// cross-block reduce of partials -> S.
// qbd: per-(b,d) sum_j S^2 ; qbj: per-(b,j) sum_d S^2 (final squash)
__device__ __forceinline__ void reduce_phase(
    const float* __restrict__ partials, float* __restrict__ S,
    float* __restrict__ qbd, float* __restrict__ qbj,
    float scale, f32x4* __restrict__ sRed4, int blk, int t)
{
  const int qd = t & 31;                 // quad index within 128-float slice
  const int dg = t >> 5;                 // depth group 0..15 (16 chunks each)
  const float* src = partials + (size_t)dg * 16 * 32768 + (size_t)blk * 128 + qd * 4;
  f32x4 ld[16];
  #pragma unroll
  for (int p = 0; p < 16; ++p) ld[p] = *(const f32x4*)(src + (size_t)p * 32768);
  f32x4 a = ld[0];
  #pragma unroll
  for (int p = 1; p < 16; ++p){ a.x += ld[p].x; a.y += ld[p].y; a.z += ld[p].z; a.w += ld[p].w; }
  sRed4[t] = a;
  __syncthreads();
  if (t < 32){
    f32x4 s = sRed4[t];
    #pragma unroll
    for (int g = 1; g < 16; ++g){
      f32x4 r = sRed4[g * 32 + t];
      s.x += r.x; s.y += r.y; s.z += r.z; s.w += r.w;
    }
    s.x *= scale; s.y *= scale; s.z *= scale; s.w *= scale;
    const int oo = blk * 128 + t * 4;
    const int k = oo & 63, ln = (oo >> 6) & 63, wd = (oo >> 12) & 3, bh = oo >> 14;
    const int b = bh * 32 + (wd & 1) * 16 + (ln & 15);
    const int j = (wd >> 1) * 16 + (k >> 2);
    const int d0 = (ln >> 4) << 2;
    *(f32x4*)(S + b * 512 + j * 16 + d0) = s;
    if (qbd){
      atomicAdd(qbd + b * 16 + d0 + 0, s.x * s.x);
      atomicAdd(qbd + b * 16 + d0 + 1, s.y * s.y);
      atomicAdd(qbd + b * 16 + d0 + 2, s.z * s.z);
      atomicAdd(qbd + b * 16 + d0 + 3, s.w * s.w);
    }
    if (qbj) atomicAdd(qbj + b * 32 + j, s.x * s.x + s.y * s.y + s.z * s.z + s.w * s.w);
  }
  __syncthreads();
}

__global__ __launch_bounds__(512, 2)
void caps_fused(const float* __restrict__ X, const float* __restrict__ W,
                unsigned int* __restrict__ gcnt,
                float* __restrict__ qb1, float* __restrict__ qb2,
                float* __restrict__ qb3,
                float* __restrict__ S1, float* __restrict__ S2, float* __restrict__ S3,
                float* __restrict__ partials, float* __restrict__ out)
{
  extern __shared__ __align__(16) char smem[];
  u16* sW = (u16*)smem;                        // [8][8192] bf16  (128 KB)
  u16* sX = (u16*)(smem + 131072);             // [8][64*16] bf16 ( 16 KB)
  float* sSumA = (float*)(smem + 147456);      // [8][16]
  float* sSumB = (float*)(smem + 147968);      // [8][16]
  f32x4* sRed4 = (f32x4*)(smem + 148480);      // [512] f32x4 (8 KB)

  const int t = threadIdx.x;
  const int blk = blockIdx.x;
  const size_t i0 = (size_t)blk * 8;

  // ---- prep: W rows fp32 -> bf16 LDS (resident for whole kernel); X likewise
  {
    const float* wsrc = W + i0 * 8192;
    #pragma unroll
    for (int k = 0; k < 16; ++k){
      int idx = k * 4096 + t * 8;
      f32x4 a = *(const f32x4*)(wsrc + idx);
      f32x4 b = *(const f32x4*)(wsrc + idx + 4);
      *(uint4v*)(sW + idx) = cvt8(a, b);
    }
    int r = t >> 6, b = t & 63;                // one (i-row, batch) per thread
    const float* xs = X + ((size_t)b * NI + i0 + (size_t)r) * 16;
    f32x4 a0 = *(const f32x4*)(xs);
    f32x4 a1 = *(const f32x4*)(xs + 4);
    f32x4 a2 = *(const f32x4*)(xs + 8);
    f32x4 a3 = *(const f32x4*)(xs + 12);
    *(uint4v*)(sX + t * 16)     = cvt8(a0, a1);
    *(uint4v*)(sX + t * 16 + 8) = cvt8(a2, a3);
  }
  __syncthreads();

  // ---- tree grid barrier with single-sided agent fences.
  // __syncthreads drains each wave's stores into L2; t0's RELEASE fence
  // writes the XCD L2 back to the coherent point; after the release word
  // is observed, t0's ACQUIRE fence invalidates stale L1/L2 lines.
  unsigned int gen = 0;
  auto gridsync = [&](bool wait){
    ++gen;
    __syncthreads();
    if (t == 0){
      __builtin_amdgcn_fence(__ATOMIC_RELEASE, "agent");   // L2 writeback
      __hip_atomic_fetch_add(gcnt + (blk & 7) * 4, 1u,
                             __ATOMIC_RELAXED, __HIP_MEMORY_SCOPE_AGENT);
      if (blk == 0){
        #pragma unroll 1
        for (int g = 0; g < 8; ++g){
          while (__hip_atomic_load(gcnt + g * 4, __ATOMIC_RELAXED,
                                   __HIP_MEMORY_SCOPE_AGENT) < gen * 32u)
            __builtin_amdgcn_s_sleep(2);
        }
        __builtin_amdgcn_fence(__ATOMIC_ACQ_REL, "agent"); // order relay
        #pragma unroll
        for (int g = 0; g < 8; ++g)
          __hip_atomic_store(gcnt + 64 + g * 64, gen,
                             __ATOMIC_RELAXED, __HIP_MEMORY_SCOPE_AGENT);
      } else if (wait){
        while (__hip_atomic_load(gcnt + 64 + (blk & 7) * 64, __ATOMIC_RELAXED,
                                 __HIP_MEMORY_SCOPE_AGENT) < gen)
          __builtin_amdgcn_s_sleep(2);
        __builtin_amdgcn_fence(__ATOMIC_ACQUIRE, "agent"); // L1/L2 invalidate
      }
    }
    __syncthreads();
  };

  // ---- routing iteration 1 (uniform c = 1/32)
  pass_phase<0>(sW, sX, sSumA, sSumB, nullptr, nullptr, nullptr, nullptr, partials, blk, t);
  gridsync(true);
  reduce_phase(partials, S1, qb1, nullptr, 1.0f / 32.0f, sRed4, blk, t);
  gridsync(true);

  // ---- routing iteration 2 (c = softmax_j(u . v1))
  pass_phase<1>(sW, sX, sSumA, sSumB, S1, qb1, nullptr, nullptr, partials, blk, t);
  gridsync(true);
  reduce_phase(partials, S2, qb2, nullptr, 1.0f, sRed4, blk, t);
  gridsync(true);

  // ---- final pass (c = softmax_j(u . (v1+v2)))
  pass_phase<2>(sW, sX, sSumA, sSumB, S1, qb1, S2, qb2, partials, blk, t);
  gridsync(true);
  reduce_phase(partials, S3, nullptr, qb3, 1.0f, sRed4, blk, t);
  gridsync(blk < 64);          // blocks >= 64 just arrive and exit

  // ---- output squash over d (axis=-1); blocks 0..63, one batch each,
  // one output element per thread. q3[b][j] accumulated by reduce above.
  if (blk < 64){
    float s = S3[blk * 512 + t];
    float q = qb3[blk * 32 + (t >> 4)];
    out[blk * 512 + t] = s * (q / ((1.f + q) * sqrtf(q + 1e-8f)));
  }
}

// ============================================================================
// Fallback path (verified 232 us ladder) — unchanged below.
// ============================================================================

__global__ __launch_bounds__(256)
void caps_prep(const float* __restrict__ W, const float* __restrict__ X,
               u16* __restrict__ Wb, u16* __restrict__ Xb)
{
  const int bid = blockIdx.x;
  if (bid < 8192){
    size_t base = (size_t)bid * 2048 + (size_t)threadIdx.x * 8;
    f32x4 a = *(const f32x4*)(W + base);
    f32x4 b = *(const f32x4*)(W + base + 4);
    *(uint4v*)(Wb + base) = cvt8(a, b);
  } else {
    int p = (bid - 8192) * 256 + threadIdx.x;   // 0..131071 = (i,b)
    int i = p >> 6, b = p & 63;
    const float* src = X + ((size_t)b * NI + i) * 16;
    f32x4 a0 = *(const f32x4*)(src);
    f32x4 a1 = *(const f32x4*)(src + 4);
    f32x4 a2 = *(const f32x4*)(src + 8);
    f32x4 a3 = *(const f32x4*)(src + 12);
    *(uint4v*)(Xb + (size_t)p * 16)     = cvt8(a0, a1);
    *(uint4v*)(Xb + (size_t)p * 16 + 8) = cvt8(a2, a3);
  }
}

template<int MODE>
__global__ __launch_bounds__(256, 2)
void caps_pass_f(const u16* __restrict__ Wb,
                 const u16* __restrict__ Xb,
                 const float* __restrict__ vbuf,
                 float* __restrict__ partials, int CI)
{
  constexpr int WR = (MODE == 0) ? 2 : 1;
  __shared__ __align__(16) u16 sW[2][WR * 8192];
  __shared__ __align__(16) u16 sX[2][WR * 512];
  __shared__ float sSum[4][16];

  const int t     = threadIdx.x;
  const int w     = t >> 6;
  const int lane  = t & 63;
  const int wtile = w & 1;
  const int jhalf = w >> 1;
  const int lq    = lane >> 4;
  const int lb    = lane & 15;
  const int q1    = lq & 1;
  const int bhalf = blockIdx.x & 1;
  const int iblk  = blockIdx.x >> 1;
  const int bloc  = wtile * 16 + lb;
  const int bg    = bhalf * 32 + bloc;
  const size_t i0 = (size_t)iblk * (size_t)CI;

  const short8 zero8 = {0,0,0,0,0,0,0,0};
  const f32x4  zf4   = {0.f,0.f,0.f,0.f};

  f32x4 acc[16];
  #pragma unroll
  for (int tj = 0; tj < 16; ++tj) acc[tj] = zf4;

  unsigned int vpl[16], vph[16];
  if constexpr (MODE == 1){
    #pragma unroll
    for (int tj = 0; tj < 16; ++tj){
      f32x4 v = *(const f32x4*)(&vbuf[bg * 512 + (jhalf * 16 + tj) * 16 + lq * 4]);
      vpl[tj] = packbf2(v.x, v.y);
      vph[tj] = packbf2(v.z, v.w);
    }
  }

  auto stage = [&](int nb, size_t irow){
    #pragma unroll
    for (int rr = 0; rr < WR; ++rr){
      const u16* src = Wb + (irow + rr) * 8192 + (size_t)(w * 4) * 512;
      u16* dst = &sW[nb][rr * 8192 + w * 4 * 512];
      #pragma unroll
      for (int r = 0; r < 4; ++r)
        gl_lds16(src + r * 512 + lane * 8, dst + r * 512);
    }
    if (w >= 4 - WR){
      int rr = w - (4 - WR);
      gl_lds16(Xb + ((irow + rr) * 64 + (size_t)bhalf * 32) * 16 + lane * 8,
               &sX[nb][rr * 512]);
    }
  };

  const int NSTEP = CI / WR;
  stage(0, i0);
  __syncthreads();

  for (int s = 0; s < NSTEP; ++s){
    const int buf = s & 1;
    if (s + 1 < NSTEP) stage(buf ^ 1, i0 + (size_t)(s + 1) * WR);

    if constexpr (MODE == 0){
      const int rsel = lq >> 1;
      short8 bfrag = *(const short8*)(&sX[buf][rsel * 512 + bloc * 16 + q1 * 8]);
      #pragma unroll
      for (int tj = 0; tj < 16; ++tj){
        int j = jhalf * 16 + tj;
        short8 afrag = *(const short8*)(&sW[buf][rsel * 8192 + j * 256 + lb * 16 + q1 * 8]);
        acc[tj] = __builtin_amdgcn_mfma_f32_16x16x32_bf16(afrag, bfrag, acc[tj], 0, 0, 0);
      }
    } else {
      short8 bl8 = *(const short8*)(&sX[buf][bloc * 16 + q1 * 8]);
      short8 bfrag = (lq < 2) ? bl8 : zero8;
      f32x4 ut[16];
      float e[16];
      float ps = 0.f;
      #pragma unroll
      for (int tj = 0; tj < 16; ++tj){
        int j = jhalf * 16 + tj;
        short8 al8 = *(const short8*)(&sW[buf][j * 256 + lb * 16 + q1 * 8]);
        short8 afrag = (lq < 2) ? al8 : zero8;
        ut[tj] = __builtin_amdgcn_mfma_f32_16x16x32_bf16(afrag, bfrag, zf4, 0, 0, 0);
        float p = ut[tj].x * bflo(vpl[tj]) + ut[tj].y * bfhi(vpl[tj])
                + ut[tj].z * bflo(vph[tj]) + ut[tj].w * bfhi(vph[tj]);
        p += __shfl_xor(p, 16, 64);
        p += __shfl_xor(p, 32, 64);
        e[tj] = __expf(p);
        ps += e[tj];
      }
      if (lane < 16) sSum[w][lane] = ps;
      __syncthreads();
      float inv = 1.0f / (ps + sSum[w ^ 2][lb]);
      #pragma unroll
      for (int tj = 0; tj < 16; ++tj){
        float c = e[tj] * inv;
        acc[tj].x += c * ut[tj].x;
        acc[tj].y += c * ut[tj].y;
        acc[tj].z += c * ut[tj].z;
        acc[tj].w += c * ut[tj].w;
      }
    }
    __syncthreads();
  }

  float* dst = partials + ((size_t)blockIdx.x * 4 + (size_t)w) * 4096 + (size_t)lane * 64;
  #pragma unroll
  for (int tj = 0; tj < 16; ++tj) *(f32x4*)(dst + tj * 4) = acc[tj];
}

template<int MODE>
__global__ __launch_bounds__(256)
void caps_pass_legacy(const float* __restrict__ Wg, const float* __restrict__ Xg,
                      const float* __restrict__ vbuf, float* __restrict__ partials, int CI)
{
  __shared__ __align__(16) unsigned short sW[2][8192];
  __shared__ __align__(16) unsigned int   sXd[2][256];
  __shared__ float sLog[(MODE == 1) ? (32 * 33) : 4];
  const int t = threadIdx.x, w = t >> 6, lane = t & 63;
  const int wtile = w & 1, jhalf = w >> 1, lq = lane >> 4, lb = lane & 15, q1 = lq & 1;
  const int bhalf = blockIdx.x & 1, iblk = blockIdx.x >> 1;
  const int bloc = wtile * 16 + lb, bg = bhalf * 32 + bloc;
  const size_t i0 = (size_t)iblk * (size_t)CI;
  const short8 zero8 = {0,0,0,0,0,0,0,0};
  const f32x4 zf4 = {0.f,0.f,0.f,0.f};
  f32x4 acc[16];
  #pragma unroll
  for (int tj = 0; tj < 16; ++tj) acc[tj] = zf4;
  unsigned int vpl[16], vph[16];
  if constexpr (MODE == 1){
    #pragma unroll
    for (int tj = 0; tj < 16; ++tj){
      f32x4 v = *(const f32x4*)(&vbuf[bg * 512 + (jhalf * 16 + tj) * 16 + lq * 4]);
      vpl[tj] = packbf2(v.x, v.y); vph[tj] = packbf2(v.z, v.w);
    }
  }
  {
    const float* wsrc = Wg + i0 * 8192;
    #pragma unroll
    for (int r = 0; r < 4; ++r){
      int c = r * 256 + t;
      f32x4 a = *(const f32x4*)(&wsrc[c * 8]);
      f32x4 b = *(const f32x4*)(&wsrc[c * 8 + 4]);
      *(uint4v*)(&sW[0][c * 8]) = cvt8(a, b);
    }
    int bidx = bhalf * 32 + (t >> 3), e2 = t & 7;
    f32x2 xv = *(const f32x2*)(&Xg[((size_t)bidx * NI + i0) * 16 + e2 * 2]);
    sXd[0][t] = packbf2(xv.x, xv.y);
  }
  __syncthreads();
  for (int s = 0; s < CI; ++s){
    const int buf = s & 1;
    f32x4 wpa[4], wpb[4]; f32x2 xp;
    const bool more = (s + 1 < CI);
    if (more){
      const float* wsrc = Wg + (i0 + (size_t)(s + 1)) * 8192;
      #pragma unroll
      for (int r = 0; r < 4; ++r){
        int c = r * 256 + t;
        wpa[r] = *(const f32x4*)(&wsrc[c * 8]);
        wpb[r] = *(const f32x4*)(&wsrc[c * 8 + 4]);
      }
      int bidx = bhalf * 32 + (t >> 3), e2 = t & 7;
      xp = *(const f32x2*)(&Xg[((size_t)bidx * NI + i0 + s + 1) * 16 + e2 * 2]);
    }
    const unsigned short* xrow = (const unsigned short*)&sXd[buf][0];
    short8 bl8 = *(const short8*)(&xrow[bloc * 16 + q1 * 8]);
    short8 bfrag = (lq < 2) ? bl8 : zero8;
    if constexpr (MODE == 0){
      #pragma unroll
      for (int tj = 0; tj < 16; ++tj){
        int j = jhalf * 16 + tj;
        short8 al8 = *(const short8*)(&sW[buf][j * 256 + lb * 16 + q1 * 8]);
        short8 afrag = (lq < 2) ? al8 : zero8;
        acc[tj] = __builtin_amdgcn_mfma_f32_16x16x32_bf16(afrag, bfrag, acc[tj], 0, 0, 0);
      }
    } else {
      #pragma unroll
      for (int tj = 0; tj < 16; ++tj){
        int j = jhalf * 16 + tj;
        short8 al8 = *(const short8*)(&sW[buf][j * 256 + lb * 16 + q1 * 8]);
        short8 afrag = (lq < 2) ? al8 : zero8;
        f32x4 u = __builtin_amdgcn_mfma_f32_16x16x32_bf16(afrag, bfrag, zf4, 0, 0, 0);
        float p = u.x * bflo(vpl[tj]) + u.y * bfhi(vpl[tj])
                + u.z * bflo(vph[tj]) + u.w * bfhi(vph[tj]);
        p += __shfl_xor(p, 16, 64);
        p += __shfl_xor(p, 32, 64);
        if (lane < 16) sLog[bloc * 33 + j] = p;
      }
      __syncthreads();
      const float* logrow = &sLog[bloc * 33];
      float ssum = 0.f;
      #pragma unroll
      for (int jj = 0; jj < 32; ++jj) ssum += __expf(logrow[jj]);
      float inv = 1.0f / ssum;
      #pragma unroll
      for (int tj = 0; tj < 16; ++tj){
        int j = jhalf * 16 + tj;
        short8 al8 = *(const short8*)(&sW[buf][j * 256 + lb * 16 + q1 * 8]);
        short8 afrag = (lq < 2) ? al8 : zero8;
        f32x4 u = __builtin_amdgcn_mfma_f32_16x16x32_bf16(afrag, bfrag, zf4, 0, 0, 0);
        float c = __expf(logrow[j]) * inv;
        acc[tj].x += c * u.x; acc[tj].y += c * u.y;
        acc[tj].z += c * u.z; acc[tj].w += c * u.w;
      }
    }
    if (more){
      const int nb = buf ^ 1;
      #pragma unroll
      for (int r = 0; r < 4; ++r){
        int c = r * 256 + t;
        *(uint4v*)(&sW[nb][c * 8]) = cvt8(wpa[r], wpb[r]);
      }
      sXd[nb][t] = packbf2(xp.x, xp.y);
    }
    __syncthreads();
  }
  float* dst = partials + ((size_t)blockIdx.x * 4 + (size_t)w) * 4096 + (size_t)lane * 64;
  #pragma unroll
  for (int tj = 0; tj < 16; ++tj) *(f32x4*)(dst + tj * 4) = acc[tj];
}

template<int NBLK>
__global__ __launch_bounds__(128)
void caps_reduce(const float* __restrict__ partials, float* __restrict__ S_buf, float scale)
{
  const int T = blockIdx.x * 128 + threadIdx.x;
  float s0 = 0.f, s1 = 0.f, s2 = 0.f, s3 = 0.f;
  #pragma unroll
  for (int bl = 0; bl < NBLK; bl += 4){
    s0 += partials[(size_t)(bl + 0) * 32768 + T];
    s1 += partials[(size_t)(bl + 1) * 32768 + T];
    s2 += partials[(size_t)(bl + 2) * 32768 + T];
    s3 += partials[(size_t)(bl + 3) * 32768 + T];
  }
  float s = ((s0 + s1) + (s2 + s3)) * scale;
  const int bhalf = T >> 14, w = (T >> 12) & 3, l = (T >> 6) & 63, k = T & 63;
  const int b  = bhalf * 32 + (w & 1) * 16 + (l & 15);
  const int jd = ((w >> 1) * 16 + (k >> 2)) * 16 + ((l >> 4) << 2) + (k & 3);
  S_buf[b * 512 + jd] = s;
}

__global__ __launch_bounds__(256)
void caps_squash_j(const float* __restrict__ S, const float* __restrict__ vprev,
                   float* __restrict__ vout)
{
  const int b = blockIdx.x, t = threadIdx.x;
  __shared__ float sq[16];
  if (t < 16) sq[t] = 0.f;
  __syncthreads();
  float s0 = S[b * 512 + t], s1 = S[b * 512 + 256 + t];
  atomicAdd(&sq[t & 15], s0 * s0 + s1 * s1);
  __syncthreads();
  float q = sq[t & 15];
  float f = q / ((1.f + q) * sqrtf(q + 1e-8f));
  float v0 = s0 * f, v1 = s1 * f;
  if (vprev){ v0 += vprev[b * 512 + t]; v1 += vprev[b * 512 + 256 + t]; }
  vout[b * 512 + t] = v0;
  vout[b * 512 + 256 + t] = v1;
}

__global__ __launch_bounds__(256)
void caps_squash_d(const float* __restrict__ S, float* __restrict__ out)
{
  const int b = blockIdx.x, t = threadIdx.x;
  __shared__ float sq[32];
  if (t < 32) sq[t] = 0.f;
  __syncthreads();
  float s0 = S[b * 512 + t], s1 = S[b * 512 + 256 + t];
  atomicAdd(&sq[t >> 4], s0 * s0);
  atomicAdd(&sq[(t + 256) >> 4], s1 * s1);
  __syncthreads();
  float q0 = sq[t >> 4], q1 = sq[(t + 256) >> 4];
  out[b * 512 + t]       = s0 * q0 / ((1.f + q0) * sqrtf(q0 + 1e-8f));
  out[b * 512 + 256 + t] = s1 * q1 / ((1.f + q1) * sqrtf(q1 + 1e-8f));
}

extern "C" void kernel_launch(void* const* d_in, const int* in_sizes, int n_in,
                              void* d_out, int out_size, void* d_ws, size_t ws_size,
                              hipStream_t stream)
{
  const float* X = (const float*)d_in[0];  // fp32 [64][2048][16]
  const float* W = (const float*)d_in[1];  // fp32 [2048][32][16][16]
  float* wsf = (float*)d_ws;

  // ---- fused-path workspace layout (floats)
  // gcnt region: 1024 uints (arrival counters at g*4; release words at 64+g*64)
  const size_t OF_Q1   = 1024;                     // q per (b,d), pass 1
  const size_t OF_Q2   = OF_Q1 + 1024;             // q per (b,d), pass 2
  const size_t OF_Q3   = OF_Q2 + 1024;             // q per (b,j), final squash
  const size_t OF_S1   = OF_Q3 + 2048;             // byte 20480, 16B aligned
  const size_t OF_S2   = OF_S1 + 32768;
  const size_t OF_S3   = OF_S2 + 32768;
  const size_t OF_PART = OF_S3 + 32768;
  const size_t FUSED_FLOATS = OF_PART + (size_t)256 * 32768;

  // one-time capability check: must fit 1 block/CU on >=256 CUs for the
  // hand-rolled grid barrier to be deadlock-free.
  static int fused_ok = -1;
  if (fused_ok < 0){
    fused_ok = 0;
    hipFuncSetAttribute(reinterpret_cast<const void*>(caps_fused),
                        hipFuncAttributeMaxDynamicSharedMemorySize, FUSED_SMEM);
    int dev = 0, ncu = 0, nb = 0;
    hipGetDevice(&dev);
    hipDeviceGetAttribute(&ncu, hipDeviceAttributeMultiprocessorCount, dev);
    hipError_t e = hipOccupancyMaxActiveBlocksPerMultiprocessor(
        &nb, caps_fused, 512, (size_t)FUSED_SMEM);
    if (e == hipSuccess && nb >= 1 && ncu >= 256) fused_ok = 1;
  }

  if (fused_ok == 1 && ws_size >= FUSED_FLOATS * 4){
    // zero barrier counters/releases + q accumulators (atomic targets)
    hipMemsetAsync(d_ws, 0, (1024 + 1024 + 1024 + 2048) * 4, stream);
    caps_fused<<<dim3(256), dim3(512), FUSED_SMEM, stream>>>(
        X, W, (unsigned int*)wsf,
        wsf + OF_Q1, wsf + OF_Q2, wsf + OF_Q3,
        wsf + OF_S1, wsf + OF_S2, wsf + OF_S3, wsf + OF_PART, (float*)d_out);
    return;
  }

  // ---- fallback: previous verified multi-kernel ladder
  const size_t FP = (size_t)256 * 32768;
  const size_t WB_ELE = (size_t)NI * 8192, XB_ELE = (size_t)NI * 64 * 16;
  const size_t need_full = (FP + 3 * 32768) * 4 + (WB_ELE + XB_ELE) * 2;

  if (ws_size >= need_full){
    float* partials = wsf;
    float* sbuf = wsf + FP;
    float* v1   = sbuf + 32768;
    float* v12  = v1 + 32768;
    u16* Wb = (u16*)(v12 + 32768);
    u16* Xb = Wb + WB_ELE;

    caps_prep<<<dim3(8704), dim3(256), 0, stream>>>(W, X, Wb, Xb);

    caps_pass_f<0><<<dim3(512), dim3(256), 0, stream>>>(Wb, Xb, nullptr, partials, 8);
    caps_reduce<256><<<dim3(256), dim3(128), 0, stream>>>(partials, sbuf, 1.0f / 32.0f);
    caps_squash_j<<<dim3(64), dim3(256), 0, stream>>>(sbuf, nullptr, v1);

    caps_pass_f<1><<<dim3(512), dim3(256), 0, stream>>>(Wb, Xb, v1, partials, 8);
    caps_reduce<256><<<dim3(256), dim3(128), 0, stream>>>(partials, sbuf, 1.0f);
    caps_squash_j<<<dim3(64), dim3(256), 0, stream>>>(sbuf, v1, v12);

    caps_pass_f<1><<<dim3(512), dim3(256), 0, stream>>>(Wb, Xb, v12, partials, 8);
    caps_reduce<256><<<dim3(256), dim3(128), 0, stream>>>(partials, sbuf, 1.0f);
    caps_squash_d<<<dim3(64), dim3(256), 0, stream>>>(sbuf, (float*)d_out);
  } else {
    int NBI = 256;
    auto need = [](int nb){ return ((size_t)nb * 32768 + 3 * 32768) * 4; };
    if (ws_size < need(256)){
      if      (ws_size >= need(64)) NBI = 64;
      else if (ws_size >= need(16)) NBI = 16;
      else                          NBI = 4;
    }
    const int CI = NI / NBI;
    float* partials = wsf;
    float* sbuf = wsf + (size_t)NBI * 32768;
    float* v1   = sbuf + 32768;
    float* v12  = v1 + 32768;
    auto reduce = [&](float scale){
      if      (NBI == 256) caps_reduce<256><<<dim3(256), dim3(128), 0, stream>>>(partials, sbuf, scale);
      else if (NBI ==  64) caps_reduce< 64><<<dim3(256), dim3(128), 0, stream>>>(partials, sbuf, scale);
      else if (NBI ==  16) caps_reduce< 16><<<dim3(256), dim3(128), 0, stream>>>(partials, sbuf, scale);
      else                 caps_reduce<  4><<<dim3(256), dim3(128), 0, stream>>>(partials, sbuf, scale);
    };
    caps_pass_legacy<0><<<dim3(2 * NBI), dim3(256), 0, stream>>>(W, X, nullptr, partials, CI);
    reduce(1.0f / 32.0f);
    caps_squash_j<<<dim3(64), dim3(256), 0, stream>>>(sbuf, nullptr, v1);
    caps_pass_legacy<1><<<dim3(2 * NBI), dim3(256), 0, stream>>>(W, X, v1, partials, CI);
    reduce(1.0f);
    caps_squash_j<<<dim3(64), dim3(256), 0, stream>>>(sbuf, v1, v12);
    caps_pass_legacy<1><<<dim3(2 * NBI), dim3(256), 0, stream>>>(W, X, v12, partials, CI);
    reduce(1.0f);
    caps_squash_d<<<dim3(64), dim3(256), 0, stream>>>(sbuf, (float*)d_out);
  }
}

// Round 5
// 231.975 us; speedup vs baseline: 1.0092x; 1.0092x over previous
//
#include <hip/hip_runtime.h>

typedef __attribute__((ext_vector_type(8))) short short8;
typedef __attribute__((ext_vector_type(4))) float f32x4;
typedef __attribute__((ext_vector_type(2))) float f32x2;
typedef __attribute__((ext_vector_type(4))) unsigned int uint4v;
typedef unsigned short u16;

#define NI 2048   // input capsules
// B=64, J=32, D=16, E=16, JD=512. Inputs fp32; compute bf16 MFMA.

// bf16 RNE pack of two floats -> dword (lo=a, hi=b)
__device__ __forceinline__ unsigned int packbf2(float a, float b){
  unsigned int ua = __float_as_uint(a), ub = __float_as_uint(b);
  unsigned int ra = (ua + 0x7FFFu + ((ua >> 16) & 1u)) >> 16;
  unsigned int rb = (ub + 0x7FFFu + ((ub >> 16) & 1u)) & 0xFFFF0000u;
  return ra | rb;
}
__device__ __forceinline__ float bflo(unsigned int p){ return __uint_as_float(p << 16); }
__device__ __forceinline__ float bfhi(unsigned int p){ return __uint_as_float(p & 0xFFFF0000u); }

__device__ __forceinline__ uint4v cvt8(const f32x4& a, const f32x4& b){
  uint4v p = { packbf2(a.x, a.y), packbf2(a.z, a.w),
               packbf2(b.x, b.y), packbf2(b.z, b.w) };
  return p;
}

// async global->LDS, 16 B per lane; lds dest = wave-uniform base + lane*16
__device__ __forceinline__ void gl_lds16(const void* g, void* l){
  __builtin_amdgcn_global_load_lds(
      (const __attribute__((address_space(1))) unsigned int*)g,
      (__attribute__((address_space(3))) unsigned int*)l, 16, 0, 0);
}

// native fp32 atomic add (never a CAS loop), no return -> fire-and-forget
__device__ __forceinline__ void atadd4(float* p, f32x4 v){
  asm volatile("global_atomic_add_f32 %0, %1, off\n\t"
               "global_atomic_add_f32 %0, %2, off offset:4\n\t"
               "global_atomic_add_f32 %0, %3, off offset:8\n\t"
               "global_atomic_add_f32 %0, %4, off offset:12"
               :: "v"(p), "v"(v.x), "v"(v.y), "v"(v.z), "v"(v.w) : "memory");
}
// write-through coherent 4B store (bypasses L1/L2 so consumers' acquire sees it)
__device__ __forceinline__ void st4_coh(float* p, float v){
  asm volatile("global_store_dword %0, %1, off sc1" :: "v"(p), "v"(v) : "memory");
}
__device__ __forceinline__ unsigned int spin_ld(const unsigned int* p){
  return __hip_atomic_load(p, __ATOMIC_RELAXED, __HIP_MEMORY_SCOPE_AGENT);
}

__device__ __forceinline__ f32x4 squash4(const f32x4& q){
  f32x4 f;
  f.x = q.x / ((1.f + q.x) * sqrtf(q.x + 1e-8f));
  f.y = q.y / ((1.f + q.y) * sqrtf(q.y + 1e-8f));
  f.z = q.z / ((1.f + q.z) * sqrtf(q.z + 1e-8f));
  f.w = q.w / ((1.f + q.w) * sqrtf(q.w + 1e-8f));
  return f;
}

// ============================================================================
// FUSED persistent kernel v3: 256 blocks x 512 threads, 1 block/CU.
// S accumulated by native fp32 atomics (coherent point) -> no partials buffer,
// no reduce phase, no release fences. Barriers: arrivals -> blocks 0..63
// compute q[b] from S (2 KB each) -> block 0 releases; consumers acquire-inv
// (cheap: nothing dirty) and read S/q through the cache path.
// ============================================================================

#define FUSED_SMEM 148608

// pass body. MODE 0: uniform c (2 i's packed into K=32), scale=1/32.
// MODE 1: c = softmax_j(u . v1), v1 = S1*f(q1).
// MODE 2: same with v12 = S1*f(q1) + S2*f(q2).
template<int MODE>
__device__ __forceinline__ void pass_phase(
    const u16* __restrict__ sW, const u16* __restrict__ sX,
    float* __restrict__ sSumA, float* __restrict__ sSumB,
    const float* __restrict__ Sv1, const float* __restrict__ qv1,
    const float* __restrict__ Sv2, const float* __restrict__ qv2,
    float* __restrict__ Sout, float scale, int blk, int t)
{
  const int w = t >> 6, lane = t & 63;
  const int wtile = w & 1, jhalf = (w >> 1) & 1, bh = w >> 2;
  const int lq = lane >> 4, lb = lane & 15, qs = lq & 1;
  const int bg = bh * 32 + wtile * 16 + lb;   // this lane's output column b
  const short8 zero8 = {0,0,0,0,0,0,0,0};
  const f32x4 zf4 = {0.f,0.f,0.f,0.f};

  f32x4 acc[16];
  #pragma unroll
  for (int tj = 0; tj < 16; ++tj) acc[tj] = zf4;

  unsigned int vpl[16], vph[16];
  if constexpr (MODE >= 1){
    // reconstruct v inline: v = S1*f(q1) (+ S2*f(q2) for MODE 2); cached reads
    f32x4 qa = *(const f32x4*)(qv1 + bg * 16 + lq * 4);
    f32x4 fa = squash4(qa);
    f32x4 fb = zf4;
    if constexpr (MODE == 2){
      f32x4 qb = *(const f32x4*)(qv2 + bg * 16 + lq * 4);
      fb = squash4(qb);
    }
    #pragma unroll
    for (int tj = 0; tj < 16; ++tj){
      int jd = (jhalf * 16 + tj) * 16 + lq * 4;
      f32x4 sv = *(const f32x4*)(Sv1 + bg * 512 + jd);
      f32x4 v;
      v.x = sv.x * fa.x; v.y = sv.y * fa.y; v.z = sv.z * fa.z; v.w = sv.w * fa.w;
      if constexpr (MODE == 2){
        f32x4 s2 = *(const f32x4*)(Sv2 + bg * 512 + jd);
        v.x += s2.x * fb.x; v.y += s2.y * fb.y; v.z += s2.z * fb.z; v.w += s2.w * fb.w;
      }
      vpl[tj] = packbf2(v.x, v.y);
      vph[tj] = packbf2(v.z, v.w);
    }
  }

  if constexpr (MODE == 0){
    // K=32 packs 2 i-rows: quads 0,1 -> row 2s, quads 2,3 -> row 2s+1
    const int rsel = lq >> 1;
    #pragma unroll
    for (int s = 0; s < 4; ++s){
      const u16* wrow = sW + (size_t)(2 * s + rsel) * 8192;
      const u16* xrow = sX + (size_t)(2 * s + rsel) * 1024;
      short8 bfrag = *(const short8*)(xrow + bg * 16 + qs * 8);
      #pragma unroll
      for (int tj = 0; tj < 16; ++tj){
        int j = jhalf * 16 + tj;
        short8 afrag = *(const short8*)(wrow + j * 256 + lb * 16 + qs * 8);
        acc[tj] = __builtin_amdgcn_mfma_f32_16x16x32_bf16(afrag, bfrag, acc[tj], 0, 0, 0);
      }
    }
  } else {
    for (int s = 0; s < 8; ++s){
      const u16* wrow = sW + (size_t)s * 8192;
      const u16* xrow = sX + (size_t)s * 1024;
      short8 bl8 = *(const short8*)(xrow + bg * 16 + qs * 8);
      short8 bfrag = (lq < 2) ? bl8 : zero8;   // K upper half zero (B-side mask suffices)
      f32x4 ut[16];
      float e[16];
      float ps = 0.f;
      #pragma unroll
      for (int tj = 0; tj < 16; ++tj){
        int j = jhalf * 16 + tj;
        short8 afrag = *(const short8*)(wrow + j * 256 + lb * 16 + qs * 8);
        ut[tj] = __builtin_amdgcn_mfma_f32_16x16x32_bf16(afrag, bfrag, zf4, 0, 0, 0);
        float p = ut[tj].x * bflo(vpl[tj]) + ut[tj].y * bfhi(vpl[tj])
                + ut[tj].z * bflo(vph[tj]) + ut[tj].w * bfhi(vph[tj]);
        p += __shfl_xor(p, 16, 64);
        p += __shfl_xor(p, 32, 64);   // full logit[j] on every lane
        e[tj] = __expf(p);            // |logit| small: fp32-safe without max-sub
        ps += e[tj];
      }
      // exchange partial denominator with j-half partner wave (w^2), A/B buffers
      float* sS = (s & 1) ? sSumB : sSumA;
      if (lane < 16) sS[w * 16 + lane] = ps;
      __syncthreads();
      float inv = 1.0f / (ps + sS[(w ^ 2) * 16 + lb]);
      #pragma unroll
      for (int tj = 0; tj < 16; ++tj){
        float c = e[tj] * inv;
        acc[tj].x += c * ut[tj].x;
        acc[tj].y += c * ut[tj].y;
        acc[tj].z += c * ut[tj].z;
        acc[tj].w += c * ut[tj].w;
      }
    }
  }

  // accumulate S directly at the coherent point (pipelined, fire-and-forget)
  #pragma unroll
  for (int tj = 0; tj < 16; ++tj){
    f32x4 v = acc[tj];
    v.x *= scale; v.y *= scale; v.z *= scale; v.w *= scale;
    atadd4(Sout + bg * 512 + (jhalf * 16 + tj) * 16 + lq * 4, v);
  }
}

__global__ __launch_bounds__(512, 2)
void caps_fused(const float* __restrict__ X, const float* __restrict__ W,
                unsigned int* __restrict__ cnt,
                float* __restrict__ q1, float* __restrict__ q2,
                float* __restrict__ S1, float* __restrict__ S2, float* __restrict__ S3,
                float* __restrict__ out)
{
  extern __shared__ __align__(16) char smem[];
  u16* sW = (u16*)smem;                        // [8][8192] bf16  (128 KB)
  u16* sX = (u16*)(smem + 131072);             // [8][64*16] bf16 ( 16 KB)
  float* sSumA = (float*)(smem + 147456);      // [8][16]
  float* sSumB = (float*)(smem + 147968);      // [8][16]
  float* sq    = (float*)(smem + 148480);      // [32]

  const int t = threadIdx.x;
  const int blk = blockIdx.x;
  const size_t i0 = (size_t)blk * 8;

  // ---- prep: W rows fp32 -> bf16 LDS (resident for whole kernel); X likewise
  {
    const float* wsrc = W + i0 * 8192;
    #pragma unroll
    for (int k = 0; k < 16; ++k){
      int idx = k * 4096 + t * 8;
      f32x4 a = *(const f32x4*)(wsrc + idx);
      f32x4 b = *(const f32x4*)(wsrc + idx + 4);
      *(uint4v*)(sW + idx) = cvt8(a, b);
    }
    int r = t >> 6, b = t & 63;                // one (i-row, batch) per thread
    const float* xs = X + ((size_t)b * NI + i0 + (size_t)r) * 16;
    f32x4 a0 = *(const f32x4*)(xs);
    f32x4 a1 = *(const f32x4*)(xs + 4);
    f32x4 a2 = *(const f32x4*)(xs + 8);
    f32x4 a3 = *(const f32x4*)(xs + 12);
    *(uint4v*)(sX + t * 16)     = cvt8(a0, a1);
    *(uint4v*)(sX + t * 16 + 8) = cvt8(a2, a3);
  }
  __syncthreads();

  // counter layout (u32): ARR(s,g)=s*8+g (s=0..2); QARR(s,g)=32+s*8+g (s=0,1);
  // REL(s,g)=128+s*128+g*16 (s=0,1). All zeroed per launch.
  // barrier + q-stage: arrivals -> blocks 0..63 compute q[b]=sum_j S^2 per d
  // -> block 0 releases. Consumers acquire-inv then read S/q cached.
  auto barrier_qstage = [&](int s, const float* Ssrc, float* qdst){
    asm volatile("s_waitcnt vmcnt(0)" ::: "memory");   // drain our atomics
    __syncthreads();
    if (blk < 64){
      if (t == 0){
        __hip_atomic_fetch_add(cnt + s * 8 + (blk & 7), 1u,
                               __ATOMIC_RELAXED, __HIP_MEMORY_SCOPE_AGENT);
        #pragma unroll 1
        for (int g = 0; g < 8; ++g)
          while (spin_ld(cnt + s * 8 + g) < 32u) __builtin_amdgcn_s_sleep(2);
        __builtin_amdgcn_fence(__ATOMIC_ACQUIRE, "agent");  // inv stale lines
      }
      __syncthreads();
      float sv_ = Ssrc[blk * 512 + t];
      if (t < 16) sq[t] = 0.f;
      __syncthreads();
      atomicAdd(&sq[t & 15], sv_ * sv_);
      __syncthreads();
      if (t < 16) st4_coh(qdst + blk * 16 + t, sq[t]);
      asm volatile("s_waitcnt vmcnt(0)" ::: "memory");
      __syncthreads();
      if (t == 0){
        __hip_atomic_fetch_add(cnt + 32 + s * 8 + (blk & 7), 1u,
                               __ATOMIC_RELAXED, __HIP_MEMORY_SCOPE_AGENT);
        if (blk == 0){
          #pragma unroll 1
          for (int g = 0; g < 8; ++g)
            while (spin_ld(cnt + 32 + s * 8 + g) < 8u) __builtin_amdgcn_s_sleep(2);
          #pragma unroll
          for (int g = 0; g < 8; ++g)
            __hip_atomic_store(cnt + 128 + s * 128 + g * 16, 1u,
                               __ATOMIC_RELAXED, __HIP_MEMORY_SCOPE_AGENT);
        } else {
          while (spin_ld(cnt + 128 + s * 128 + (blk & 7) * 16) == 0u)
            __builtin_amdgcn_s_sleep(2);
        }
        __builtin_amdgcn_fence(__ATOMIC_ACQUIRE, "agent");  // see fresh q
      }
      __syncthreads();
    } else {
      if (t == 0){
        __hip_atomic_fetch_add(cnt + s * 8 + (blk & 7), 1u,
                               __ATOMIC_RELAXED, __HIP_MEMORY_SCOPE_AGENT);
        while (spin_ld(cnt + 128 + s * 128 + (blk & 7) * 16) == 0u)
          __builtin_amdgcn_s_sleep(2);
        __builtin_amdgcn_fence(__ATOMIC_ACQUIRE, "agent");
      }
      __syncthreads();
    }
  };

  // ---- routing iteration 1 (uniform c = 1/32) -> S1
  pass_phase<0>(sW, sX, sSumA, sSumB, nullptr, nullptr, nullptr, nullptr,
                S1, 1.0f / 32.0f, blk, t);
  barrier_qstage(0, S1, q1);

  // ---- routing iteration 2 (c = softmax_j(u . v1)) -> S2
  pass_phase<1>(sW, sX, sSumA, sSumB, S1, q1, nullptr, nullptr,
                S2, 1.0f, blk, t);
  barrier_qstage(1, S2, q2);

  // ---- final pass (c = softmax_j(u . (v1+v2))) -> S3
  pass_phase<2>(sW, sX, sSumA, sSumB, S1, q1, S2, q2,
                S3, 1.0f, blk, t);

  // ---- final stage: arrive; blocks 0..63 squash over d and write out. No release.
  asm volatile("s_waitcnt vmcnt(0)" ::: "memory");
  __syncthreads();
  if (t == 0)
    __hip_atomic_fetch_add(cnt + 16 + (blk & 7), 1u,
                           __ATOMIC_RELAXED, __HIP_MEMORY_SCOPE_AGENT);
  if (blk < 64){
    if (t == 0){
      #pragma unroll 1
      for (int g = 0; g < 8; ++g)
        while (spin_ld(cnt + 16 + g) < 32u) __builtin_amdgcn_s_sleep(2);
      __builtin_amdgcn_fence(__ATOMIC_ACQUIRE, "agent");
    }
    __syncthreads();
    float sv_ = S3[blk * 512 + t];
    if (t < 32) sq[t] = 0.f;
    __syncthreads();
    atomicAdd(&sq[t >> 4], sv_ * sv_);
    __syncthreads();
    float qq = sq[t >> 4];
    out[blk * 512 + t] = sv_ * (qq / ((1.f + qq) * sqrtf(qq + 1e-8f)));
  }
}

// ============================================================================
// Fallback path (verified 232 us ladder) — unchanged below.
// ============================================================================

__global__ __launch_bounds__(256)
void caps_prep(const float* __restrict__ W, const float* __restrict__ X,
               u16* __restrict__ Wb, u16* __restrict__ Xb)
{
  const int bid = blockIdx.x;
  if (bid < 8192){
    size_t base = (size_t)bid * 2048 + (size_t)threadIdx.x * 8;
    f32x4 a = *(const f32x4*)(W + base);
    f32x4 b = *(const f32x4*)(W + base + 4);
    *(uint4v*)(Wb + base) = cvt8(a, b);
  } else {
    int p = (bid - 8192) * 256 + threadIdx.x;   // 0..131071 = (i,b)
    int i = p >> 6, b = p & 63;
    const float* src = X + ((size_t)b * NI + i) * 16;
    f32x4 a0 = *(const f32x4*)(src);
    f32x4 a1 = *(const f32x4*)(src + 4);
    f32x4 a2 = *(const f32x4*)(src + 8);
    f32x4 a3 = *(const f32x4*)(src + 12);
    *(uint4v*)(Xb + (size_t)p * 16)     = cvt8(a0, a1);
    *(uint4v*)(Xb + (size_t)p * 16 + 8) = cvt8(a2, a3);
  }
}

template<int MODE>
__global__ __launch_bounds__(256, 2)
void caps_pass_f(const u16* __restrict__ Wb,
                 const u16* __restrict__ Xb,
                 const float* __restrict__ vbuf,
                 float* __restrict__ partials, int CI)
{
  constexpr int WR = (MODE == 0) ? 2 : 1;
  __shared__ __align__(16) u16 sW[2][WR * 8192];
  __shared__ __align__(16) u16 sX[2][WR * 512];
  __shared__ float sSum[4][16];

  const int t     = threadIdx.x;
  const int w     = t >> 6;
  const int lane  = t & 63;
  const int wtile = w & 1;
  const int jhalf = w >> 1;
  const int lq    = lane >> 4;
  const int lb    = lane & 15;
  const int q1    = lq & 1;
  const int bhalf = blockIdx.x & 1;
  const int iblk  = blockIdx.x >> 1;
  const int bloc  = wtile * 16 + lb;
  const int bg    = bhalf * 32 + bloc;
  const size_t i0 = (size_t)iblk * (size_t)CI;

  const short8 zero8 = {0,0,0,0,0,0,0,0};
  const f32x4  zf4   = {0.f,0.f,0.f,0.f};

  f32x4 acc[16];
  #pragma unroll
  for (int tj = 0; tj < 16; ++tj) acc[tj] = zf4;

  unsigned int vpl[16], vph[16];
  if constexpr (MODE == 1){
    #pragma unroll
    for (int tj = 0; tj < 16; ++tj){
      f32x4 v = *(const f32x4*)(&vbuf[bg * 512 + (jhalf * 16 + tj) * 16 + lq * 4]);
      vpl[tj] = packbf2(v.x, v.y);
      vph[tj] = packbf2(v.z, v.w);
    }
  }

  auto stage = [&](int nb, size_t irow){
    #pragma unroll
    for (int rr = 0; rr < WR; ++rr){
      const u16* src = Wb + (irow + rr) * 8192 + (size_t)(w * 4) * 512;
      u16* dst = &sW[nb][rr * 8192 + w * 4 * 512];
      #pragma unroll
      for (int r = 0; r < 4; ++r)
        gl_lds16(src + r * 512 + lane * 8, dst + r * 512);
    }
    if (w >= 4 - WR){
      int rr = w - (4 - WR);
      gl_lds16(Xb + ((irow + rr) * 64 + (size_t)bhalf * 32) * 16 + lane * 8,
               &sX[nb][rr * 512]);
    }
  };

  const int NSTEP = CI / WR;
  stage(0, i0);
  __syncthreads();

  for (int s = 0; s < NSTEP; ++s){
    const int buf = s & 1;
    if (s + 1 < NSTEP) stage(buf ^ 1, i0 + (size_t)(s + 1) * WR);

    if constexpr (MODE == 0){
      const int rsel = lq >> 1;
      short8 bfrag = *(const short8*)(&sX[buf][rsel * 512 + bloc * 16 + q1 * 8]);
      #pragma unroll
      for (int tj = 0; tj < 16; ++tj){
        int j = jhalf * 16 + tj;
        short8 afrag = *(const short8*)(&sW[buf][rsel * 8192 + j * 256 + lb * 16 + q1 * 8]);
        acc[tj] = __builtin_amdgcn_mfma_f32_16x16x32_bf16(afrag, bfrag, acc[tj], 0, 0, 0);
      }
    } else {
      short8 bl8 = *(const short8*)(&sX[buf][bloc * 16 + q1 * 8]);
      short8 bfrag = (lq < 2) ? bl8 : zero8;
      f32x4 ut[16];
      float e[16];
      float ps = 0.f;
      #pragma unroll
      for (int tj = 0; tj < 16; ++tj){
        int j = jhalf * 16 + tj;
        short8 al8 = *(const short8*)(&sW[buf][j * 256 + lb * 16 + q1 * 8]);
        short8 afrag = (lq < 2) ? al8 : zero8;
        ut[tj] = __builtin_amdgcn_mfma_f32_16x16x32_bf16(afrag, bfrag, zf4, 0, 0, 0);
        float p = ut[tj].x * bflo(vpl[tj]) + ut[tj].y * bfhi(vpl[tj])
                + ut[tj].z * bflo(vph[tj]) + ut[tj].w * bfhi(vph[tj]);
        p += __shfl_xor(p, 16, 64);
        p += __shfl_xor(p, 32, 64);
        e[tj] = __expf(p);
        ps += e[tj];
      }
      if (lane < 16) sSum[w][lane] = ps;
      __syncthreads();
      float inv = 1.0f / (ps + sSum[w ^ 2][lb]);
      #pragma unroll
      for (int tj = 0; tj < 16; ++tj){
        float c = e[tj] * inv;
        acc[tj].x += c * ut[tj].x;
        acc[tj].y += c * ut[tj].y;
        acc[tj].z += c * ut[tj].z;
        acc[tj].w += c * ut[tj].w;
      }
    }
    __syncthreads();
  }

  float* dst = partials + ((size_t)blockIdx.x * 4 + (size_t)w) * 4096 + (size_t)lane * 64;
  #pragma unroll
  for (int tj = 0; tj < 16; ++tj) *(f32x4*)(dst + tj * 4) = acc[tj];
}

template<int MODE>
__global__ __launch_bounds__(256)
void caps_pass_legacy(const float* __restrict__ Wg, const float* __restrict__ Xg,
                      const float* __restrict__ vbuf, float* __restrict__ partials, int CI)
{
  __shared__ __align__(16) unsigned short sW[2][8192];
  __shared__ __align__(16) unsigned int   sXd[2][256];
  __shared__ float sLog[(MODE == 1) ? (32 * 33) : 4];
  const int t = threadIdx.x, w = t >> 6, lane = t & 63;
  const int wtile = w & 1, jhalf = w >> 1, lq = lane >> 4, lb = lane & 15, q1 = lq & 1;
  const int bhalf = blockIdx.x & 1, iblk = blockIdx.x >> 1;
  const int bloc = wtile * 16 + lb, bg = bhalf * 32 + bloc;
  const size_t i0 = (size_t)iblk * (size_t)CI;
  const short8 zero8 = {0,0,0,0,0,0,0,0};
  const f32x4 zf4 = {0.f,0.f,0.f,0.f};
  f32x4 acc[16];
  #pragma unroll
  for (int tj = 0; tj < 16; ++tj) acc[tj] = zf4;
  unsigned int vpl[16], vph[16];
  if constexpr (MODE == 1){
    #pragma unroll
    for (int tj = 0; tj < 16; ++tj){
      f32x4 v = *(const f32x4*)(&vbuf[bg * 512 + (jhalf * 16 + tj) * 16 + lq * 4]);
      vpl[tj] = packbf2(v.x, v.y); vph[tj] = packbf2(v.z, v.w);
    }
  }
  {
    const float* wsrc = Wg + i0 * 8192;
    #pragma unroll
    for (int r = 0; r < 4; ++r){
      int c = r * 256 + t;
      f32x4 a = *(const f32x4*)(&wsrc[c * 8]);
      f32x4 b = *(const f32x4*)(&wsrc[c * 8 + 4]);
      *(uint4v*)(&sW[0][c * 8]) = cvt8(a, b);
    }
    int bidx = bhalf * 32 + (t >> 3), e2 = t & 7;
    f32x2 xv = *(const f32x2*)(&Xg[((size_t)bidx * NI + i0) * 16 + e2 * 2]);
    sXd[0][t] = packbf2(xv.x, xv.y);
  }
  __syncthreads();
  for (int s = 0; s < CI; ++s){
    const int buf = s & 1;
    f32x4 wpa[4], wpb[4]; f32x2 xp;
    const bool more = (s + 1 < CI);
    if (more){
      const float* wsrc = Wg + (i0 + (size_t)(s + 1)) * 8192;
      #pragma unroll
      for (int r = 0; r < 4; ++r){
        int c = r * 256 + t;
        wpa[r] = *(const f32x4*)(&wsrc[c * 8]);
        wpb[r] = *(const f32x4*)(&wsrc[c * 8 + 4]);
      }
      int bidx = bhalf * 32 + (t >> 3), e2 = t & 7;
      xp = *(const f32x2*)(&Xg[((size_t)bidx * NI + i0 + s + 1) * 16 + e2 * 2]);
    }
    const unsigned short* xrow = (const unsigned short*)&sXd[buf][0];
    short8 bl8 = *(const short8*)(&xrow[bloc * 16 + q1 * 8]);
    short8 bfrag = (lq < 2) ? bl8 : zero8;
    if constexpr (MODE == 0){
      #pragma unroll
      for (int tj = 0; tj < 16; ++tj){
        int j = jhalf * 16 + tj;
        short8 al8 = *(const short8*)(&sW[buf][j * 256 + lb * 16 + q1 * 8]);
        short8 afrag = (lq < 2) ? al8 : zero8;
        acc[tj] = __builtin_amdgcn_mfma_f32_16x16x32_bf16(afrag, bfrag, acc[tj], 0, 0, 0);
      }
    } else {
      #pragma unroll
      for (int tj = 0; tj < 16; ++tj){
        int j = jhalf * 16 + tj;
        short8 al8 = *(const short8*)(&sW[buf][j * 256 + lb * 16 + q1 * 8]);
        short8 afrag = (lq < 2) ? al8 : zero8;
        f32x4 u = __builtin_amdgcn_mfma_f32_16x16x32_bf16(afrag, bfrag, zf4, 0, 0, 0);
        float p = u.x * bflo(vpl[tj]) + u.y * bfhi(vpl[tj])
                + u.z * bflo(vph[tj]) + u.w * bfhi(vph[tj]);
        p += __shfl_xor(p, 16, 64);
        p += __shfl_xor(p, 32, 64);
        if (lane < 16) sLog[bloc * 33 + j] = p;
      }
      __syncthreads();
      const float* logrow = &sLog[bloc * 33];
      float ssum = 0.f;
      #pragma unroll
      for (int jj = 0; jj < 32; ++jj) ssum += __expf(logrow[jj]);
      float inv = 1.0f / ssum;
      #pragma unroll
      for (int tj = 0; tj < 16; ++tj){
        int j = jhalf * 16 + tj;
        short8 al8 = *(const short8*)(&sW[buf][j * 256 + lb * 16 + q1 * 8]);
        short8 afrag = (lq < 2) ? al8 : zero8;
        f32x4 u = __builtin_amdgcn_mfma_f32_16x16x32_bf16(afrag, bfrag, zf4, 0, 0, 0);
        float c = __expf(logrow[j]) * inv;
        acc[tj].x += c * u.x; acc[tj].y += c * u.y;
        acc[tj].z += c * u.z; acc[tj].w += c * u.w;
      }
    }
    if (more){
      const int nb = buf ^ 1;
      #pragma unroll
      for (int r = 0; r < 4; ++r){
        int c = r * 256 + t;
        *(uint4v*)(&sW[nb][c * 8]) = cvt8(wpa[r], wpb[r]);
      }
      sXd[nb][t] = packbf2(xp.x, xp.y);
    }
    __syncthreads();
  }
  float* dst = partials + ((size_t)blockIdx.x * 4 + (size_t)w) * 4096 + (size_t)lane * 64;
  #pragma unroll
  for (int tj = 0; tj < 16; ++tj) *(f32x4*)(dst + tj * 4) = acc[tj];
}

template<int NBLK>
__global__ __launch_bounds__(128)
void caps_reduce(const float* __restrict__ partials, float* __restrict__ S_buf, float scale)
{
  const int T = blockIdx.x * 128 + threadIdx.x;
  float s0 = 0.f, s1 = 0.f, s2 = 0.f, s3 = 0.f;
  #pragma unroll
  for (int bl = 0; bl < NBLK; bl += 4){
    s0 += partials[(size_t)(bl + 0) * 32768 + T];
    s1 += partials[(size_t)(bl + 1) * 32768 + T];
    s2 += partials[(size_t)(bl + 2) * 32768 + T];
    s3 += partials[(size_t)(bl + 3) * 32768 + T];
  }
  float s = ((s0 + s1) + (s2 + s3)) * scale;
  const int bhalf = T >> 14, w = (T >> 12) & 3, l = (T >> 6) & 63, k = T & 63;
  const int b  = bhalf * 32 + (w & 1) * 16 + (l & 15);
  const int jd = ((w >> 1) * 16 + (k >> 2)) * 16 + ((l >> 4) << 2) + (k & 3);
  S_buf[b * 512 + jd] = s;
}

__global__ __launch_bounds__(256)
void caps_squash_j(const float* __restrict__ S, const float* __restrict__ vprev,
                   float* __restrict__ vout)
{
  const int b = blockIdx.x, t = threadIdx.x;
  __shared__ float sq[16];
  if (t < 16) sq[t] = 0.f;
  __syncthreads();
  float s0 = S[b * 512 + t], s1 = S[b * 512 + 256 + t];
  atomicAdd(&sq[t & 15], s0 * s0 + s1 * s1);
  __syncthreads();
  float q = sq[t & 15];
  float f = q / ((1.f + q) * sqrtf(q + 1e-8f));
  float v0 = s0 * f, v1 = s1 * f;
  if (vprev){ v0 += vprev[b * 512 + t]; v1 += vprev[b * 512 + 256 + t]; }
  vout[b * 512 + t] = v0;
  vout[b * 512 + 256 + t] = v1;
}

__global__ __launch_bounds__(256)
void caps_squash_d(const float* __restrict__ S, float* __restrict__ out)
{
  const int b = blockIdx.x, t = threadIdx.x;
  __shared__ float sq[32];
  if (t < 32) sq[t] = 0.f;
  __syncthreads();
  float s0 = S[b * 512 + t], s1 = S[b * 512 + 256 + t];
  atomicAdd(&sq[t >> 4], s0 * s0);
  atomicAdd(&sq[(t + 256) >> 4], s1 * s1);
  __syncthreads();
  float q0 = sq[t >> 4], q1 = sq[(t + 256) >> 4];
  out[b * 512 + t]       = s0 * q0 / ((1.f + q0) * sqrtf(q0 + 1e-8f));
  out[b * 512 + 256 + t] = s1 * q1 / ((1.f + q1) * sqrtf(q1 + 1e-8f));
}

extern "C" void kernel_launch(void* const* d_in, const int* in_sizes, int n_in,
                              void* d_out, int out_size, void* d_ws, size_t ws_size,
                              hipStream_t stream)
{
  const float* X = (const float*)d_in[0];  // fp32 [64][2048][16]
  const float* W = (const float*)d_in[1];  // fp32 [2048][32][16][16]
  float* wsf = (float*)d_ws;

  // ---- fused-path workspace layout (floats)
  const size_t OF_Q1 = 1024;               // cnt: 1024 u32 at offset 0
  const size_t OF_Q2 = OF_Q1 + 1024;
  const size_t OF_S1 = OF_Q2 + 1024;       // byte 12288, 16B aligned
  const size_t OF_S2 = OF_S1 + 32768;
  const size_t OF_S3 = OF_S2 + 32768;
  const size_t FUSED_FLOATS = OF_S3 + 32768;

  // one-time capability check: must fit 1 block/CU on >=256 CUs for the
  // hand-rolled grid barrier to be deadlock-free.
  static int fused_ok = -1;
  if (fused_ok < 0){
    fused_ok = 0;
    hipFuncSetAttribute(reinterpret_cast<const void*>(caps_fused),
                        hipFuncAttributeMaxDynamicSharedMemorySize, FUSED_SMEM);
    int dev = 0, ncu = 0, nb = 0;
    hipGetDevice(&dev);
    hipDeviceGetAttribute(&ncu, hipDeviceAttributeMultiprocessorCount, dev);
    hipError_t e = hipOccupancyMaxActiveBlocksPerMultiprocessor(
        &nb, caps_fused, 512, (size_t)FUSED_SMEM);
    if (e == hipSuccess && nb >= 1 && ncu >= 256) fused_ok = 1;
  }

  if (fused_ok == 1 && ws_size >= FUSED_FLOATS * 4){
    // zero counters + atomic accumulators S1..S3 (q1/q2 fully overwritten)
    hipMemsetAsync(d_ws, 0, FUSED_FLOATS * 4, stream);
    caps_fused<<<dim3(256), dim3(512), FUSED_SMEM, stream>>>(
        X, W, (unsigned int*)wsf,
        wsf + OF_Q1, wsf + OF_Q2,
        wsf + OF_S1, wsf + OF_S2, wsf + OF_S3, (float*)d_out);
    return;
  }

  // ---- fallback: previous verified multi-kernel ladder
  const size_t FP = (size_t)256 * 32768;
  const size_t WB_ELE = (size_t)NI * 8192, XB_ELE = (size_t)NI * 64 * 16;
  const size_t need_full = (FP + 3 * 32768) * 4 + (WB_ELE + XB_ELE) * 2;

  if (ws_size >= need_full){
    float* partials = wsf;
    float* sbuf = wsf + FP;
    float* v1   = sbuf + 32768;
    float* v12  = v1 + 32768;
    u16* Wb = (u16*)(v12 + 32768);
    u16* Xb = Wb + WB_ELE;

    caps_prep<<<dim3(8704), dim3(256), 0, stream>>>(W, X, Wb, Xb);

    caps_pass_f<0><<<dim3(512), dim3(256), 0, stream>>>(Wb, Xb, nullptr, partials, 8);
    caps_reduce<256><<<dim3(256), dim3(128), 0, stream>>>(partials, sbuf, 1.0f / 32.0f);
    caps_squash_j<<<dim3(64), dim3(256), 0, stream>>>(sbuf, nullptr, v1);

    caps_pass_f<1><<<dim3(512), dim3(256), 0, stream>>>(Wb, Xb, v1, partials, 8);
    caps_reduce<256><<<dim3(256), dim3(128), 0, stream>>>(partials, sbuf, 1.0f);
    caps_squash_j<<<dim3(64), dim3(256), 0, stream>>>(sbuf, v1, v12);

    caps_pass_f<1><<<dim3(512), dim3(256), 0, stream>>>(Wb, Xb, v12, partials, 8);
    caps_reduce<256><<<dim3(256), dim3(128), 0, stream>>>(partials, sbuf, 1.0f);
    caps_squash_d<<<dim3(64), dim3(256), 0, stream>>>(sbuf, (float*)d_out);
  } else {
    int NBI = 256;
    auto need = [](int nb){ return ((size_t)nb * 32768 + 3 * 32768) * 4; };
    if (ws_size < need(256)){
      if      (ws_size >= need(64)) NBI = 64;
      else if (ws_size >= need(16)) NBI = 16;
      else                          NBI = 4;
    }
    const int CI = NI / NBI;
    float* partials = wsf;
    float* sbuf = wsf + (size_t)NBI * 32768;
    float* v1   = sbuf + 32768;
    float* v12  = v1 + 32768;
    auto reduce = [&](float scale){
      if      (NBI == 256) caps_reduce<256><<<dim3(256), dim3(128), 0, stream>>>(partials, sbuf, scale);
      else if (NBI ==  64) caps_reduce< 64><<<dim3(256), dim3(128), 0, stream>>>(partials, sbuf, scale);
      else if (NBI ==  16) caps_reduce< 16><<<dim3(256), dim3(128), 0, stream>>>(partials, sbuf, scale);
      else                 caps_reduce<  4><<<dim3(256), dim3(128), 0, stream>>>(partials, sbuf, scale);
    };
    caps_pass_legacy<0><<<dim3(2 * NBI), dim3(256), 0, stream>>>(W, X, nullptr, partials, CI);
    reduce(1.0f / 32.0f);
    caps_squash_j<<<dim3(64), dim3(256), 0, stream>>>(sbuf, nullptr, v1);
    caps_pass_legacy<1><<<dim3(2 * NBI), dim3(256), 0, stream>>>(W, X, v1, partials, CI);
    reduce(1.0f);
    caps_squash_j<<<dim3(64), dim3(256), 0, stream>>>(sbuf, v1, v12);
    caps_pass_legacy<1><<<dim3(2 * NBI), dim3(256), 0, stream>>>(W, X, v12, partials, CI);
    reduce(1.0f);
    caps_squash_d<<<dim3(64), dim3(256), 0, stream>>>(sbuf, (float*)d_out);
  }
}